// Round 8
// baseline (406.802 us; speedup 1.0000x reference)
//
#include <hip/hip_runtime.h>
#include <math.h>

#define N_ROWS 32768
#define DIM 256
#define K_CODES 1024
#define MARGIN 2e-3f

typedef float f32x4v __attribute__((ext_vector_type(4)));
typedef short s16x8 __attribute__((ext_vector_type(8)));

// ---- ws layout (bytes) ----
// x2    float[32768]        @ 0
// w2    float[1024]         @ 131072
// whi   ushort[262144]      @ 135168
// wlo   ushort[262144]      @ 659456
// flags uint[2048]          @ 1183744   (one 16-bit mask per 16-row block)
#define WS_NEEDED ((size_t)1191936)

__device__ __forceinline__ unsigned short bf16_rne(float f) {
    unsigned int u = __float_as_uint(f);
    unsigned int r = (u + 0x7FFFu + ((u >> 16) & 1u)) >> 16;
    return (unsigned short)r;
}
__device__ __forceinline__ float bf16_f32(unsigned short h) {
    return __uint_as_float(((unsigned int)h) << 16);
}

// ---------------------------------------------------------------------------
// numpy-replica pairwise sum of squares (AVX512 path) — bitwise == np.sum(x*x)
// ---------------------------------------------------------------------------
__device__ __forceinline__ float np_block128_sumsq(const float* e) {
#pragma clang fp contract(off)
    float s[16];
#pragma unroll
    for (int l = 0; l < 16; ++l) {
        float a0 = e[l]       * e[l];
        float a1 = e[16 + l]  * e[16 + l];
        float a2 = e[32 + l]  * e[32 + l];
        float a3 = e[48 + l]  * e[48 + l];
        float a4 = e[64 + l]  * e[64 + l];
        float a5 = e[80 + l]  * e[80 + l];
        float a6 = e[96 + l]  * e[96 + l];
        float a7 = e[112 + l] * e[112 + l];
        s[l] = ((a0 + a1) + (a2 + a3)) + ((a4 + a5) + (a6 + a7));
    }
    float t1[8];
#pragma unroll
    for (int i = 0; i < 8; ++i) t1[i] = s[i] + s[i + 8];
    float t2[4];
#pragma unroll
    for (int i = 0; i < 4; ++i) t2[i] = t1[i] + t1[i + 4];
    return (t2[0] + t2[2]) + (t2[1] + t2[3]);
}

__global__ __launch_bounds__(64) void npsumsq_kernel(const float* __restrict__ src,
                                                     float* __restrict__ dst) {
    __shared__ float buf[16][257];
    const int tid = threadIdx.x;
    const int r0 = blockIdx.x * 16;
#pragma unroll
    for (int it = 0; it < 16; ++it) {
        int idx = it * 64 + tid;
        int r = idx >> 6, c4 = idx & 63;
        float4 v = ((const float4*)(src + (size_t)(r0 + r) * DIM))[c4];
        buf[r][c4 * 4 + 0] = v.x;
        buf[r][c4 * 4 + 1] = v.y;
        buf[r][c4 * 4 + 2] = v.z;
        buf[r][c4 * 4 + 3] = v.w;
    }
    __syncthreads();
    if (tid < 16) {
        const float* e = buf[tid];
        dst[r0 + tid] = np_block128_sumsq(e) + np_block128_sumsq(e + 128);
    }
}

// ---------------------------------------------------------------------------
// wprep: w2 (np tree) + bf16 hi/lo split, 16 codes per 64-thread block.
// ---------------------------------------------------------------------------
__global__ __launch_bounds__(64) void wprep_kernel(const float* __restrict__ w,
                                                   float* __restrict__ w2,
                                                   unsigned short* __restrict__ whi,
                                                   unsigned short* __restrict__ wlo) {
    __shared__ float buf[16][257];
    const int tid = threadIdx.x;
    const int r0 = blockIdx.x * 16;
#pragma unroll
    for (int it = 0; it < 16; ++it) {
        int idx = it * 64 + tid;
        int r = idx >> 6, c4 = idx & 63;
        float4 v = ((const float4*)(w + (size_t)(r0 + r) * DIM))[c4];
        buf[r][c4 * 4 + 0] = v.x;
        buf[r][c4 * 4 + 1] = v.y;
        buf[r][c4 * 4 + 2] = v.z;
        buf[r][c4 * 4 + 3] = v.w;
        // split this float4 -> ushort4 hi/lo (coalesced 8B stores)
        ushort4 h, l;
        float e[4] = {v.x, v.y, v.z, v.w};
        unsigned short hh[4], ll[4];
#pragma unroll
        for (int i = 0; i < 4; ++i) {
            hh[i] = bf16_rne(e[i]);
            ll[i] = bf16_rne(e[i] - bf16_f32(hh[i]));
        }
        h.x = hh[0]; h.y = hh[1]; h.z = hh[2]; h.w = hh[3];
        l.x = ll[0]; l.y = ll[1]; l.z = ll[2]; l.w = ll[3];
        size_t g = (size_t)(r0 + r) * (DIM / 4) + c4;
        ((ushort4*)whi)[g] = h;
        ((ushort4*)wlo)[g] = l;
    }
    __syncthreads();
    if (tid < 16) {
        const float* e = buf[tid];
        w2[r0 + tid] = np_block128_sumsq(e) + np_block128_sumsq(e + 128);
    }
}

// ---------------------------------------------------------------------------
// Main: block = 16 rows x 1024 codes; 4 waves each own 256 codes.
// 3 independent MFMA accumulator chains (hi.hi, hi.lo, lo.hi).
// Per-block top-2 merge (wave-ascending = code-ascending -> np tie-break),
// margin flag bitmask, fused z_q gather.
// Fragment mappings as verified in round 7 (absmax=0):
//   A: row=lane&15, k=(lane>>4)*8+i ; B: col=lane&15, same k ; D: col=lane&15,
//   row=(lane>>4)*4+j.
// ---------------------------------------------------------------------------
__global__ __launch_bounds__(256) void vq_mfma(
    const float* __restrict__ x, const unsigned short* __restrict__ whi,
    const unsigned short* __restrict__ wlo, const float* __restrict__ x2g,
    const float* __restrict__ w2g, const float* __restrict__ w,
    float* __restrict__ zout, float* __restrict__ zq,
    unsigned int* __restrict__ flags) {
    __shared__ float L1[4][16], L2[4][16];
    __shared__ int LI[4][16];
    __shared__ int widx[16];

    const int tid = threadIdx.x;
    const int wave = tid >> 6;
    const int lane = tid & 63;
    const int rowbase = blockIdx.x * 16;
    const int kgrp = (lane >> 4) * 8;

    // ---- build A fragments (each wave builds its own copy of the 16 rows) ----
    s16x8 ahi[8], alo[8];
    {
        const float* xr = x + (size_t)(rowbase + (lane & 15)) * DIM + kgrp;
#pragma unroll
        for (int q = 0; q < 8; ++q) {
            float4 v0 = *(const float4*)(xr + q * 32);
            float4 v1 = *(const float4*)(xr + q * 32 + 4);
            float e[8] = {v0.x, v0.y, v0.z, v0.w, v1.x, v1.y, v1.z, v1.w};
#pragma unroll
            for (int i = 0; i < 8; ++i) {
                unsigned short h = bf16_rne(e[i]);
                ahi[q][i] = (short)h;
                alo[q][i] = (short)bf16_rne(e[i] - bf16_f32(h));
            }
        }
    }

    float x2v[4];
#pragma unroll
    for (int j = 0; j < 4; ++j) x2v[j] = x2g[rowbase + (lane >> 4) * 4 + j];

    float b1[4], b2[4];
    int i1[4];
#pragma unroll
    for (int j = 0; j < 4; ++j) { b1[j] = INFINITY; b2[j] = INFINITY; i1[j] = 0; }

    // wave's code range: [wave*256, wave*256+256)
    for (int ct = 0; ct < 16; ++ct) {
        const int code = wave * 256 + ct * 16 + (lane & 15);
        const unsigned short* bh = whi + (size_t)code * DIM + kgrp;
        const unsigned short* bl = wlo + (size_t)code * DIM + kgrp;
        f32x4v ahh = {0.f, 0.f, 0.f, 0.f};
        f32x4v ahl = {0.f, 0.f, 0.f, 0.f};
        f32x4v alh = {0.f, 0.f, 0.f, 0.f};
#pragma unroll
        for (int q = 0; q < 8; ++q) {
            s16x8 Bh = *(const s16x8*)(bh + q * 32);
            s16x8 Bl = *(const s16x8*)(bl + q * 32);
            ahh = __builtin_amdgcn_mfma_f32_16x16x32_bf16(ahi[q], Bh, ahh, 0, 0, 0);
            ahl = __builtin_amdgcn_mfma_f32_16x16x32_bf16(ahi[q], Bl, ahl, 0, 0, 0);
            alh = __builtin_amdgcn_mfma_f32_16x16x32_bf16(alo[q], Bh, alh, 0, 0, 0);
        }
        float w2v = w2g[code];
#pragma unroll
        for (int j = 0; j < 4; ++j) {
            float dot = (ahh[j] + ahl[j]) + alh[j];
            float s = (x2v[j] - 2.0f * dot) + w2v;
            if (s < b2[j]) {
                if (s < b1[j]) { b2[j] = b1[j]; b1[j] = s; i1[j] = code; }
                else b2[j] = s;
            }
        }
    }

    // butterfly top-2 reduce across the 16-lane col group (masks 1,2,4,8)
#pragma unroll
    for (int m = 1; m < 16; m <<= 1) {
#pragma unroll
        for (int j = 0; j < 4; ++j) {
            float ov1 = __shfl_xor(b1[j], m);
            int oi = __shfl_xor(i1[j], m);
            float ov2 = __shfl_xor(b2[j], m);
            float nb2 = fminf(fmaxf(b1[j], ov1), fminf(b2[j], ov2));
            if (ov1 < b1[j] || (ov1 == b1[j] && oi < i1[j])) { b1[j] = ov1; i1[j] = oi; }
            b2[j] = nb2;
        }
    }
    if ((lane & 15) == 0) {
#pragma unroll
        for (int j = 0; j < 4; ++j) {
            int r = (lane >> 4) * 4 + j;
            L1[wave][r] = b1[j];
            L2[wave][r] = b2[j];
            LI[wave][r] = i1[j];
        }
    }
    __syncthreads();

    // merge 4 waves in ascending code order; write zout; flag near-ties
    bool flg = false;
    if (tid < 16) {
        float g1 = INFINITY, g2 = INFINITY;
        int gi = 0;
#pragma unroll
        for (int ww = 0; ww < 4; ++ww) {
            float v1 = L1[ww][tid], v2 = L2[ww][tid];
            int vi = LI[ww][tid];
            float n2 = fminf(fmaxf(g1, v1), fminf(g2, v2));
            if (v1 < g1) { g1 = v1; gi = vi; }
            g2 = n2;
        }
        widx[tid] = gi;
        zout[rowbase + tid] = (float)gi;
        flg = (g2 - g1 < MARGIN);
    }
    unsigned long long bal = __ballot(flg);   // whole wave participates
    if (tid == 0) flags[blockIdx.x] = (unsigned int)(bal & 0xFFFFull);
    __syncthreads();

    // fused gather: 16 rows x 64 float4
    const float4* w4 = (const float4*)w;
    float4* zq4 = (float4*)zq;
#pragma unroll
    for (int p = 0; p < 4; ++p) {
        int lin = p * 256 + tid;
        int row = lin >> 6, q = lin & 63;
        zq4[(size_t)(rowbase + row) * 64 + q] = w4[(size_t)widx[row] * 64 + q];
    }
}

// ---------------------------------------------------------------------------
// Exact np-f32 rescore of flagged rows (round-5-verified semantics); also
// rewrites the z_q row.
// ---------------------------------------------------------------------------
__global__ __launch_bounds__(256) void rescue_kernel(
    const float* __restrict__ x, const float* __restrict__ w,
    const float* __restrict__ x2g, const float* __restrict__ w2g,
    const unsigned int* __restrict__ flags, float* __restrict__ zout,
    float* __restrict__ zq) {
    __shared__ float xs[DIM];
    __shared__ float dv[256];
    __shared__ int di[256];
    __shared__ int mi_s;
    const int tid = threadIdx.x;
    unsigned int f = flags[blockIdx.x];
    if (f == 0) return;
    while (f) {
        int j = __ffs(f) - 1;
        f &= f - 1;
        const int r = blockIdx.x * 16 + j;
        __syncthreads();
        for (int i = tid; i < DIM; i += 256) xs[i] = x[(size_t)r * DIM + i];
        __syncthreads();
        const float x2vv = x2g[r];
        float bv = INFINITY;
        int bi = 0;
#pragma unroll
        for (int cc = 0; cc < 4; ++cc) {
            int c = tid + cc * 256;   // ascending per thread
            const float* wr = w + (size_t)c * DIM;
            float dot = 0.f;
            for (int k = 0; k < DIM; ++k) dot = __builtin_fmaf(xs[k], wr[k], dot);
            float s = (x2vv - 2.0f * dot) + w2g[c];
            if (s < bv) { bv = s; bi = c; }
        }
        dv[tid] = bv;
        di[tid] = bi;
        __syncthreads();
        if (tid == 0) {
            float mv = dv[0];
            int mi = di[0];
            for (int t = 1; t < 256; ++t)
                if (dv[t] < mv || (dv[t] == mv && di[t] < mi)) { mv = dv[t]; mi = di[t]; }
            zout[r] = (float)mi;
            mi_s = mi;
        }
        __syncthreads();
        zq[(size_t)r * DIM + tid] = w[(size_t)mi_s * DIM + tid];
    }
}

// ===========================================================================
// Fallback (round-5 passing LDS kernel) if ws is too small. Needs only x2/w2.
// ===========================================================================
#define BM 64
#define BN 128
#define BK 64
#define LDX 68

__global__ __launch_bounds__(256) void vq_kernel_lds(
    const float* __restrict__ x, const float* __restrict__ w,
    const float* __restrict__ x2g, const float* __restrict__ w2g,
    float* __restrict__ zout, float* __restrict__ zq) {
    __shared__ float xs[BM * LDX];
    __shared__ float ws_[BN * LDX];
    __shared__ float sw2[K_CODES];
    __shared__ float sx2[BM];
    __shared__ int widx[BM];

    const int tid = threadIdx.x;
    const int bm0 = blockIdx.x * BM;
    const int rg = tid & 15;
    const int cg = tid >> 4;

    for (int i = tid; i < K_CODES; i += 256) sw2[i] = w2g[i];
    if (tid < BM) sx2[tid] = x2g[bm0 + tid];

    float best[4];
    int bidx[4];
#pragma unroll
    for (int i = 0; i < 4; ++i) { best[i] = INFINITY; bidx[i] = 0; }

    const float4* x4 = (const float4*)x;
    const float4* w4 = (const float4*)w;

    for (int cn = 0; cn < K_CODES / BN; ++cn) {
        float acc[4][8];
#pragma unroll
        for (int i = 0; i < 4; ++i)
#pragma unroll
            for (int j = 0; j < 8; ++j) acc[i][j] = 0.f;

        for (int dk = 0; dk < DIM / BK; ++dk) {
            __syncthreads();
#pragma unroll
            for (int p = 0; p < 4; ++p) {
                int l = p * 256 + tid;
                int row = l >> 4, c4 = l & 15;
                float4 v = x4[(size_t)(bm0 + row) * (DIM / 4) + dk * (BK / 4) + c4];
                *(float4*)&xs[row * LDX + c4 * 4] = v;
            }
#pragma unroll
            for (int p = 0; p < 8; ++p) {
                int l = p * 256 + tid;
                int row = l >> 4, c4 = l & 15;
                float4 v = w4[(size_t)(cn * BN + row) * (DIM / 4) + dk * (BK / 4) + c4];
                *(float4*)&ws_[row * LDX + c4 * 4] = v;
            }
            __syncthreads();
#pragma unroll
            for (int d = 0; d < BK; d += 4) {
                float4 xv[4], wv[8];
#pragma unroll
                for (int i = 0; i < 4; ++i)
                    xv[i] = *(const float4*)&xs[(rg + 16 * i) * LDX + d];
#pragma unroll
                for (int j = 0; j < 8; ++j)
                    wv[j] = *(const float4*)&ws_[(cg + 16 * j) * LDX + d];
#pragma unroll
                for (int i = 0; i < 4; ++i)
#pragma unroll
                    for (int j = 0; j < 8; ++j) {
                        acc[i][j] = __builtin_fmaf(xv[i].x, wv[j].x, acc[i][j]);
                        acc[i][j] = __builtin_fmaf(xv[i].y, wv[j].y, acc[i][j]);
                        acc[i][j] = __builtin_fmaf(xv[i].z, wv[j].z, acc[i][j]);
                        acc[i][j] = __builtin_fmaf(xv[i].w, wv[j].w, acc[i][j]);
                    }
            }
        }
#pragma unroll
        for (int j = 0; j < 8; ++j) {
            int c = cn * BN + cg + 16 * j;
            float w2v = sw2[c];
#pragma unroll
            for (int i = 0; i < 4; ++i) {
                float t = sx2[rg + 16 * i] - 2.0f * acc[i][j];
                float s = t + w2v;
                if (s < best[i]) { best[i] = s; bidx[i] = c; }
            }
        }
    }

    __syncthreads();
    float* sval = xs;
    int* sidx = (int*)(xs + 64 * 17);
#pragma unroll
    for (int i = 0; i < 4; ++i) {
        sval[(rg + 16 * i) * 17 + cg] = best[i];
        sidx[(rg + 16 * i) * 17 + cg] = bidx[i];
    }
    __syncthreads();
    if (tid < BM) {
        float bv = INFINITY;
        int bi = 0;
        for (int c = 0; c < 16; ++c) {
            float v = sval[tid * 17 + c];
            int id = sidx[tid * 17 + c];
            if (v < bv || (v == bv && id < bi)) { bv = v; bi = id; }
        }
        widx[tid] = bi;
        zout[bm0 + tid] = (float)bi;
    }
    __syncthreads();
    float4* zq4 = (float4*)zq;
#pragma unroll
    for (int p = 0; p < 16; ++p) {
        int lin = p * 256 + tid;
        int row = lin >> 6, q = lin & 63;
        zq4[(size_t)(bm0 + row) * 64 + q] = w4[(size_t)widx[row] * 64 + q];
    }
}

extern "C" void kernel_launch(void* const* d_in, const int* in_sizes, int n_in,
                              void* d_out, int out_size, void* d_ws, size_t ws_size,
                              hipStream_t stream) {
    const float* z_e = (const float*)d_in[0];
    const float* emb = (const float*)d_in[1];
    float* x2g = (float*)d_ws;                                   // [32768]
    float* w2g = x2g + N_ROWS;                                   // [1024]
    unsigned short* whi = (unsigned short*)(w2g + K_CODES);      // [262144]
    unsigned short* wlo = whi + (size_t)K_CODES * DIM;           // [262144]
    unsigned int* flags = (unsigned int*)(wlo + (size_t)K_CODES * DIM);  // [2048]
    float* zout = (float*)d_out;                                 // [32768]
    float* zq = (float*)d_out + N_ROWS;                          // [32768*256]

    npsumsq_kernel<<<N_ROWS / 16, 64, 0, stream>>>(z_e, x2g);

    if (ws_size >= WS_NEEDED) {
        wprep_kernel<<<K_CODES / 16, 64, 0, stream>>>(emb, w2g, whi, wlo);
        vq_mfma<<<N_ROWS / 16, 256, 0, stream>>>(z_e, whi, wlo, x2g, w2g, emb,
                                                 zout, zq, flags);
        rescue_kernel<<<N_ROWS / 16, 256, 0, stream>>>(z_e, emb, x2g, w2g,
                                                       flags, zout, zq);
    } else {
        npsumsq_kernel<<<K_CODES / 16, 64, 0, stream>>>(emb, w2g);
        vq_kernel_lds<<<N_ROWS / BM, 256, 0, stream>>>(z_e, emb, x2g, w2g, zout, zq);
    }
}

// Round 9
// 312.592 us; speedup vs baseline: 1.3014x; 1.3014x over previous
//
#include <hip/hip_runtime.h>
#include <math.h>

#define N_ROWS 32768
#define DIM 256
#define K_CODES 1024
#define MARGIN 2e-3f

typedef float f32x4v __attribute__((ext_vector_type(4)));
typedef short s16x8 __attribute__((ext_vector_type(8)));

// ---- ws layout (bytes) ----
// x2    float[32768]        @ 0          (fallback path only)
// w2    float[1024]         @ 131072
// whi   ushort[262144]      @ 135168
// wlo   ushort[262144]      @ 659456
// flags uint[1024]          @ 1183744   (one 32-bit mask per 32-row block)
#define WS_NEEDED ((size_t)1191936)

__device__ __forceinline__ unsigned short bf16_rne(float f) {
    unsigned int u = __float_as_uint(f);
    unsigned int r = (u + 0x7FFFu + ((u >> 16) & 1u)) >> 16;
    return (unsigned short)r;
}
__device__ __forceinline__ float bf16_f32(unsigned short h) {
    return __uint_as_float(((unsigned int)h) << 16);
}

// ---------------------------------------------------------------------------
// numpy-replica pairwise sum of squares (AVX512 path) — bitwise == np.sum(x*x)
// ---------------------------------------------------------------------------
__device__ __forceinline__ float np_block128_sumsq(const float* e) {
#pragma clang fp contract(off)
    float s[16];
#pragma unroll
    for (int l = 0; l < 16; ++l) {
        float a0 = e[l]       * e[l];
        float a1 = e[16 + l]  * e[16 + l];
        float a2 = e[32 + l]  * e[32 + l];
        float a3 = e[48 + l]  * e[48 + l];
        float a4 = e[64 + l]  * e[64 + l];
        float a5 = e[80 + l]  * e[80 + l];
        float a6 = e[96 + l]  * e[96 + l];
        float a7 = e[112 + l] * e[112 + l];
        s[l] = ((a0 + a1) + (a2 + a3)) + ((a4 + a5) + (a6 + a7));
    }
    float t1[8];
#pragma unroll
    for (int i = 0; i < 8; ++i) t1[i] = s[i] + s[i + 8];
    float t2[4];
#pragma unroll
    for (int i = 0; i < 4; ++i) t2[i] = t1[i] + t1[i + 4];
    return (t2[0] + t2[2]) + (t2[1] + t2[3]);
}

__global__ __launch_bounds__(64) void npsumsq_kernel(const float* __restrict__ src,
                                                     float* __restrict__ dst) {
    __shared__ float buf[16][257];
    const int tid = threadIdx.x;
    const int r0 = blockIdx.x * 16;
#pragma unroll
    for (int it = 0; it < 16; ++it) {
        int idx = it * 64 + tid;
        int r = idx >> 6, c4 = idx & 63;
        float4 v = ((const float4*)(src + (size_t)(r0 + r) * DIM))[c4];
        buf[r][c4 * 4 + 0] = v.x;
        buf[r][c4 * 4 + 1] = v.y;
        buf[r][c4 * 4 + 2] = v.z;
        buf[r][c4 * 4 + 3] = v.w;
    }
    __syncthreads();
    if (tid < 16) {
        const float* e = buf[tid];
        dst[r0 + tid] = np_block128_sumsq(e) + np_block128_sumsq(e + 128);
    }
}

// ---------------------------------------------------------------------------
// X -> bf16 hi/lo split into scratch (the z_q output region; rewritten later).
// ---------------------------------------------------------------------------
__global__ __launch_bounds__(256) void xsplit_kernel(const float* __restrict__ x,
                                                     unsigned short* __restrict__ xhi,
                                                     unsigned short* __restrict__ xlo) {
    size_t i = (size_t)blockIdx.x * 256 + threadIdx.x;   // float4 index
    float4 v = ((const float4*)x)[i];
    float e[4] = {v.x, v.y, v.z, v.w};
    ushort4 h, l;
    unsigned short hh[4], ll[4];
#pragma unroll
    for (int k = 0; k < 4; ++k) {
        hh[k] = bf16_rne(e[k]);
        ll[k] = bf16_rne(e[k] - bf16_f32(hh[k]));
    }
    h.x = hh[0]; h.y = hh[1]; h.z = hh[2]; h.w = hh[3];
    l.x = ll[0]; l.y = ll[1]; l.z = ll[2]; l.w = ll[3];
    ((ushort4*)xhi)[i] = h;
    ((ushort4*)xlo)[i] = l;
}

// ---------------------------------------------------------------------------
// wprep: w2 (np tree) + bf16 hi/lo split, 16 codes per 64-thread block.
// ---------------------------------------------------------------------------
__global__ __launch_bounds__(64) void wprep_kernel(const float* __restrict__ w,
                                                   float* __restrict__ w2,
                                                   unsigned short* __restrict__ whi,
                                                   unsigned short* __restrict__ wlo) {
    __shared__ float buf[16][257];
    const int tid = threadIdx.x;
    const int r0 = blockIdx.x * 16;
#pragma unroll
    for (int it = 0; it < 16; ++it) {
        int idx = it * 64 + tid;
        int r = idx >> 6, c4 = idx & 63;
        float4 v = ((const float4*)(w + (size_t)(r0 + r) * DIM))[c4];
        buf[r][c4 * 4 + 0] = v.x;
        buf[r][c4 * 4 + 1] = v.y;
        buf[r][c4 * 4 + 2] = v.z;
        buf[r][c4 * 4 + 3] = v.w;
        ushort4 h, l;
        float e[4] = {v.x, v.y, v.z, v.w};
        unsigned short hh[4], ll[4];
#pragma unroll
        for (int i = 0; i < 4; ++i) {
            hh[i] = bf16_rne(e[i]);
            ll[i] = bf16_rne(e[i] - bf16_f32(hh[i]));
        }
        h.x = hh[0]; h.y = hh[1]; h.z = hh[2]; h.w = hh[3];
        l.x = ll[0]; l.y = ll[1]; l.z = ll[2]; l.w = ll[3];
        size_t g = (size_t)(r0 + r) * (DIM / 4) + c4;
        ((ushort4*)whi)[g] = h;
        ((ushort4*)wlo)[g] = l;
    }
    __syncthreads();
    if (tid < 16) {
        const float* e = buf[tid];
        w2[r0 + tid] = np_block128_sumsq(e) + np_block128_sumsq(e + 128);
    }
}

// ---------------------------------------------------------------------------
// Main: block = 32 rows x 1024 codes; 4 waves each own 256 codes, share rows.
// Per wave: 2 A-row-frags (rows 0-15, 16-31) x 8 k-chunks, hi+lo from xhi/xlo.
// Score = w2 - 2*dot  (x2 dropped: row-constant, shifts all scores equally up
// to np-rounding skew <= 1.2e-4 << MARGIN; rescue handles near-ties exactly).
// Fragment mappings as verified in rounds 7/8 (absmax=0).
// ---------------------------------------------------------------------------
__global__ __launch_bounds__(256, 2) void vq_mfma(
    const unsigned short* __restrict__ xhi, const unsigned short* __restrict__ xlo,
    const unsigned short* __restrict__ whi, const unsigned short* __restrict__ wlo,
    const float* __restrict__ w2g, float* __restrict__ zout,
    unsigned int* __restrict__ flags) {
    __shared__ float L1s[4][32], L2s[4][32];
    __shared__ int LIs[4][32];

    const int tid = threadIdx.x;
    const int wave = tid >> 6;
    const int lane = tid & 63;
    const int rowbase = blockIdx.x * 32;
    const int kgrp = (lane >> 4) * 8;

    // ---- A fragments: 2 row-frags x 8 q x (hi,lo), pure 16B loads ----
    s16x8 ahi0[8], alo0[8], ahi1[8], alo1[8];
    {
        const unsigned short* xr0 = xhi + (size_t)(rowbase + (lane & 15)) * DIM + kgrp;
        const unsigned short* xl0 = xlo + (size_t)(rowbase + (lane & 15)) * DIM + kgrp;
#pragma unroll
        for (int q = 0; q < 8; ++q) {
            ahi0[q] = *(const s16x8*)(xr0 + q * 32);
            alo0[q] = *(const s16x8*)(xl0 + q * 32);
            ahi1[q] = *(const s16x8*)(xr0 + 16 * DIM + q * 32);
            alo1[q] = *(const s16x8*)(xl0 + 16 * DIM + q * 32);
        }
    }

    float b1[2][4], b2[2][4];
    int i1[2][4];
#pragma unroll
    for (int rf = 0; rf < 2; ++rf)
#pragma unroll
        for (int j = 0; j < 4; ++j) { b1[rf][j] = INFINITY; b2[rf][j] = INFINITY; i1[rf][j] = 0; }

    for (int ct = 0; ct < 16; ++ct) {
        const int code = wave * 256 + ct * 16 + (lane & 15);
        const unsigned short* bh = whi + (size_t)code * DIM + kgrp;
        const unsigned short* bl = wlo + (size_t)code * DIM + kgrp;
        f32x4v a0hh = {0.f, 0.f, 0.f, 0.f};
        f32x4v a0hl = {0.f, 0.f, 0.f, 0.f};
        f32x4v a0lh = {0.f, 0.f, 0.f, 0.f};
        f32x4v a1hh = {0.f, 0.f, 0.f, 0.f};
        f32x4v a1hl = {0.f, 0.f, 0.f, 0.f};
        f32x4v a1lh = {0.f, 0.f, 0.f, 0.f};
#pragma unroll
        for (int q = 0; q < 8; ++q) {
            s16x8 Bh = *(const s16x8*)(bh + q * 32);
            s16x8 Bl = *(const s16x8*)(bl + q * 32);
            a0hh = __builtin_amdgcn_mfma_f32_16x16x32_bf16(ahi0[q], Bh, a0hh, 0, 0, 0);
            a0hl = __builtin_amdgcn_mfma_f32_16x16x32_bf16(ahi0[q], Bl, a0hl, 0, 0, 0);
            a0lh = __builtin_amdgcn_mfma_f32_16x16x32_bf16(alo0[q], Bh, a0lh, 0, 0, 0);
            a1hh = __builtin_amdgcn_mfma_f32_16x16x32_bf16(ahi1[q], Bh, a1hh, 0, 0, 0);
            a1hl = __builtin_amdgcn_mfma_f32_16x16x32_bf16(ahi1[q], Bl, a1hl, 0, 0, 0);
            a1lh = __builtin_amdgcn_mfma_f32_16x16x32_bf16(alo1[q], Bh, a1lh, 0, 0, 0);
        }
        float w2v = w2g[code];
#pragma unroll
        for (int j = 0; j < 4; ++j) {
            float d0 = (a0hh[j] + a0hl[j]) + a0lh[j];
            float s0 = w2v - 2.0f * d0;
            if (s0 < b2[0][j]) {
                if (s0 < b1[0][j]) { b2[0][j] = b1[0][j]; b1[0][j] = s0; i1[0][j] = code; }
                else b2[0][j] = s0;
            }
            float d1 = (a1hh[j] + a1hl[j]) + a1lh[j];
            float s1 = w2v - 2.0f * d1;
            if (s1 < b2[1][j]) {
                if (s1 < b1[1][j]) { b2[1][j] = b1[1][j]; b1[1][j] = s1; i1[1][j] = code; }
                else b2[1][j] = s1;
            }
        }
    }

    // butterfly top-2 reduce across the 16-lane col group (masks 1,2,4,8)
#pragma unroll
    for (int m = 1; m < 16; m <<= 1) {
#pragma unroll
        for (int rf = 0; rf < 2; ++rf)
#pragma unroll
            for (int j = 0; j < 4; ++j) {
                float ov1 = __shfl_xor(b1[rf][j], m);
                int oi = __shfl_xor(i1[rf][j], m);
                float ov2 = __shfl_xor(b2[rf][j], m);
                float nb2 = fminf(fmaxf(b1[rf][j], ov1), fminf(b2[rf][j], ov2));
                if (ov1 < b1[rf][j] || (ov1 == b1[rf][j] && oi < i1[rf][j])) {
                    b1[rf][j] = ov1; i1[rf][j] = oi;
                }
                b2[rf][j] = nb2;
            }
    }
    if ((lane & 15) == 0) {
#pragma unroll
        for (int rf = 0; rf < 2; ++rf)
#pragma unroll
            for (int j = 0; j < 4; ++j) {
                int r = (lane >> 4) * 4 + j + 16 * rf;
                L1s[wave][r] = b1[rf][j];
                L2s[wave][r] = b2[rf][j];
                LIs[wave][r] = i1[rf][j];
            }
    }
    __syncthreads();

    // merge 4 waves in ascending code order; write zout; flag near-ties
    bool flg = false;
    if (tid < 32) {
        float g1 = INFINITY, g2 = INFINITY;
        int gi = 0;
#pragma unroll
        for (int ww = 0; ww < 4; ++ww) {
            float v1 = L1s[ww][tid], v2 = L2s[ww][tid];
            int vi = LIs[ww][tid];
            float n2 = fminf(fmaxf(g1, v1), fminf(g2, v2));
            if (v1 < g1) { g1 = v1; gi = vi; }
            g2 = n2;
        }
        zout[rowbase + tid] = (float)gi;
        flg = (g2 - g1 < MARGIN);
    }
    unsigned long long bal = __ballot(flg);   // wave 0; bits 0..31 = rows
    if (tid == 0) flags[blockIdx.x] = (unsigned int)(bal & 0xFFFFFFFFull);
}

// ---------------------------------------------------------------------------
// Gather z_q from final indices (runs after ALL vq_mfma blocks — the xhi/xlo
// scratch it overwrites is no longer needed).
// ---------------------------------------------------------------------------
__global__ __launch_bounds__(256) void gather_kernel(const float* __restrict__ zout,
                                                     const float* __restrict__ w,
                                                     float* __restrict__ zq) {
    const int tid = threadIdx.x;
    const int bm0 = blockIdx.x * 16;
    __shared__ int widx[16];
    if (tid < 16) widx[tid] = (int)zout[bm0 + tid];
    __syncthreads();
    const float4* w4 = (const float4*)w;
    float4* zq4 = (float4*)zq;
#pragma unroll
    for (int p = 0; p < 4; ++p) {
        int lin = p * 256 + tid;
        int row = lin >> 6, q = lin & 63;
        zq4[(size_t)(bm0 + row) * 64 + q] = w4[(size_t)widx[row] * 64 + q];
    }
}

// ---------------------------------------------------------------------------
// Exact np-f32 rescore of flagged rows (round-5-verified semantics), with
// np-exact x2 computed in-kernel; rewrites zout + the z_q row.
// ---------------------------------------------------------------------------
__global__ __launch_bounds__(256) void rescue_kernel(
    const float* __restrict__ x, const float* __restrict__ w,
    const float* __restrict__ w2g, const unsigned int* __restrict__ flags,
    float* __restrict__ zout, float* __restrict__ zq) {
    __shared__ float xs[DIM];
    __shared__ float dv[256];
    __shared__ int di[256];
    __shared__ int mi_s;
    __shared__ float x2_s;
    const int tid = threadIdx.x;
    unsigned int f = flags[blockIdx.x];
    if (f == 0) return;
    while (f) {
        int j = __ffs(f) - 1;
        f &= f - 1;
        const int r = blockIdx.x * 32 + j;
        __syncthreads();
        for (int i = tid; i < DIM; i += 256) xs[i] = x[(size_t)r * DIM + i];
        __syncthreads();
        if (tid == 0)
            x2_s = np_block128_sumsq(xs) + np_block128_sumsq(xs + 128);
        __syncthreads();
        const float x2vv = x2_s;
        float bv = INFINITY;
        int bi = 0;
#pragma unroll
        for (int cc = 0; cc < 4; ++cc) {
            int c = tid + cc * 256;   // ascending per thread
            const float* wr = w + (size_t)c * DIM;
            float dot = 0.f;
            for (int k = 0; k < DIM; ++k) dot = __builtin_fmaf(xs[k], wr[k], dot);
            float s = (x2vv - 2.0f * dot) + w2g[c];
            if (s < bv) { bv = s; bi = c; }
        }
        dv[tid] = bv;
        di[tid] = bi;
        __syncthreads();
        if (tid == 0) {
            float mv = dv[0];
            int mi = di[0];
            for (int t = 1; t < 256; ++t)
                if (dv[t] < mv || (dv[t] == mv && di[t] < mi)) { mv = dv[t]; mi = di[t]; }
            zout[r] = (float)mi;
            mi_s = mi;
        }
        __syncthreads();
        zq[(size_t)r * DIM + tid] = w[(size_t)mi_s * DIM + tid];
    }
}

// ===========================================================================
// Fallback (round-5 passing LDS kernel) if ws is too small. Needs only x2/w2.
// ===========================================================================
#define BM 64
#define BN 128
#define BK 64
#define LDX 68

__global__ __launch_bounds__(256) void vq_kernel_lds(
    const float* __restrict__ x, const float* __restrict__ w,
    const float* __restrict__ x2g, const float* __restrict__ w2g,
    float* __restrict__ zout, float* __restrict__ zq) {
    __shared__ float xs[BM * LDX];
    __shared__ float ws_[BN * LDX];
    __shared__ float sw2[K_CODES];
    __shared__ float sx2[BM];
    __shared__ int widx[BM];

    const int tid = threadIdx.x;
    const int bm0 = blockIdx.x * BM;
    const int rg = tid & 15;
    const int cg = tid >> 4;

    for (int i = tid; i < K_CODES; i += 256) sw2[i] = w2g[i];
    if (tid < BM) sx2[tid] = x2g[bm0 + tid];

    float best[4];
    int bidx[4];
#pragma unroll
    for (int i = 0; i < 4; ++i) { best[i] = INFINITY; bidx[i] = 0; }

    const float4* x4 = (const float4*)x;
    const float4* w4 = (const float4*)w;

    for (int cn = 0; cn < K_CODES / BN; ++cn) {
        float acc[4][8];
#pragma unroll
        for (int i = 0; i < 4; ++i)
#pragma unroll
            for (int j = 0; j < 8; ++j) acc[i][j] = 0.f;

        for (int dk = 0; dk < DIM / BK; ++dk) {
            __syncthreads();
#pragma unroll
            for (int p = 0; p < 4; ++p) {
                int l = p * 256 + tid;
                int row = l >> 4, c4 = l & 15;
                float4 v = x4[(size_t)(bm0 + row) * (DIM / 4) + dk * (BK / 4) + c4];
                *(float4*)&xs[row * LDX + c4 * 4] = v;
            }
#pragma unroll
            for (int p = 0; p < 8; ++p) {
                int l = p * 256 + tid;
                int row = l >> 4, c4 = l & 15;
                float4 v = w4[(size_t)(cn * BN + row) * (DIM / 4) + dk * (BK / 4) + c4];
                *(float4*)&ws_[row * LDX + c4 * 4] = v;
            }
            __syncthreads();
#pragma unroll
            for (int d = 0; d < BK; d += 4) {
                float4 xv[4], wv[8];
#pragma unroll
                for (int i = 0; i < 4; ++i)
                    xv[i] = *(const float4*)&xs[(rg + 16 * i) * LDX + d];
#pragma unroll
                for (int j = 0; j < 8; ++j)
                    wv[j] = *(const float4*)&ws_[(cg + 16 * j) * LDX + d];
#pragma unroll
                for (int i = 0; i < 4; ++i)
#pragma unroll
                    for (int j = 0; j < 8; ++j) {
                        acc[i][j] = __builtin_fmaf(xv[i].x, wv[j].x, acc[i][j]);
                        acc[i][j] = __builtin_fmaf(xv[i].y, wv[j].y, acc[i][j]);
                        acc[i][j] = __builtin_fmaf(xv[i].z, wv[j].z, acc[i][j]);
                        acc[i][j] = __builtin_fmaf(xv[i].w, wv[j].w, acc[i][j]);
                    }
            }
        }
#pragma unroll
        for (int j = 0; j < 8; ++j) {
            int c = cn * BN + cg + 16 * j;
            float w2v = sw2[c];
#pragma unroll
            for (int i = 0; i < 4; ++i) {
                float t = sx2[rg + 16 * i] - 2.0f * acc[i][j];
                float s = t + w2v;
                if (s < best[i]) { best[i] = s; bidx[i] = c; }
            }
        }
    }

    __syncthreads();
    float* sval = xs;
    int* sidx = (int*)(xs + 64 * 17);
#pragma unroll
    for (int i = 0; i < 4; ++i) {
        sval[(rg + 16 * i) * 17 + cg] = best[i];
        sidx[(rg + 16 * i) * 17 + cg] = bidx[i];
    }
    __syncthreads();
    if (tid < BM) {
        float bv = INFINITY;
        int bi = 0;
        for (int c = 0; c < 16; ++c) {
            float v = sval[tid * 17 + c];
            int id = sidx[tid * 17 + c];
            if (v < bv || (v == bv && id < bi)) { bv = v; bi = id; }
        }
        widx[tid] = bi;
        zout[bm0 + tid] = (float)bi;
    }
    __syncthreads();
    float4* zq4 = (float4*)zq;
#pragma unroll
    for (int p = 0; p < 16; ++p) {
        int lin = p * 256 + tid;
        int row = lin >> 6, q = lin & 63;
        zq4[(size_t)(bm0 + row) * 64 + q] = w4[(size_t)widx[row] * 64 + q];
    }
}

extern "C" void kernel_launch(void* const* d_in, const int* in_sizes, int n_in,
                              void* d_out, int out_size, void* d_ws, size_t ws_size,
                              hipStream_t stream) {
    const float* z_e = (const float*)d_in[0];
    const float* emb = (const float*)d_in[1];
    float* x2g = (float*)d_ws;                                   // [32768] (fallback)
    float* w2g = x2g + N_ROWS;                                   // [1024]
    unsigned short* whi = (unsigned short*)(w2g + K_CODES);      // [262144]
    unsigned short* wlo = whi + (size_t)K_CODES * DIM;           // [262144]
    unsigned int* flags = (unsigned int*)(wlo + (size_t)K_CODES * DIM);  // [1024]
    float* zout = (float*)d_out;                                 // [32768]
    float* zq = (float*)d_out + N_ROWS;                          // [32768*256]
    // X hi/lo scratch lives in the zq region (exactly 32 MB); gather (after
    // all vq_mfma blocks) and rescue rewrite every byte of zq afterwards.
    unsigned short* xhi = (unsigned short*)zq;                   // 16 MB
    unsigned short* xlo = xhi + (size_t)N_ROWS * DIM;            // 16 MB

    if (ws_size >= WS_NEEDED) {
        xsplit_kernel<<<N_ROWS * DIM / 4 / 256, 256, 0, stream>>>(z_e, xhi, xlo);
        wprep_kernel<<<K_CODES / 16, 64, 0, stream>>>(emb, w2g, whi, wlo);
        vq_mfma<<<N_ROWS / 32, 256, 0, stream>>>(xhi, xlo, whi, wlo, w2g,
                                                 zout, flags);
        gather_kernel<<<N_ROWS / 16, 256, 0, stream>>>(zout, emb, zq);
        rescue_kernel<<<N_ROWS / 32, 256, 0, stream>>>(z_e, emb, w2g, flags,
                                                       zout, zq);
    } else {
        npsumsq_kernel<<<N_ROWS / 16, 64, 0, stream>>>(z_e, x2g);
        npsumsq_kernel<<<K_CODES / 16, 64, 0, stream>>>(emb, w2g);
        vq_kernel_lds<<<N_ROWS / BM, 256, 0, stream>>>(z_e, emb, x2g, w2g, zout, zq);
    }
}